// Round 6
// baseline (180.527 us; speedup 1.0000x reference)
//
#include <hip/hip_runtime.h>

#define BB 256
#define TT 256
#define CC 256
#define HH 64

typedef _Float16 half8 __attribute__((ext_vector_type(8)));
typedef _Float16 half4 __attribute__((ext_vector_type(4)));
typedef float floatx4 __attribute__((ext_vector_type(4)));

// ---------------------------------------------------------------------------
// prep: blocks 0..63   -> rpeh[i] = (f16) rpe[i]           (256*64 elems)
//       blocks 64..255 -> WT[(w*64+n)][k] = (f16) W_w[k][n] (transposed f16)
// ---------------------------------------------------------------------------
__global__ __launch_bounds__(256) void prep(
    const float* __restrict__ rpe,
    const float* __restrict__ Wk, const float* __restrict__ Wq, const float* __restrict__ Wv,
    _Float16* __restrict__ rpeh, _Float16* __restrict__ WT)
{
    const int bid = blockIdx.x, tid = threadIdx.x;
    if (bid < 64) {
        const int i = bid * 256 + tid;
        rpeh[i] = (_Float16)rpe[i];
    } else {
        const int wsel = (bid - 64) >> 6;          // 0=k, 1=q, 2=v
        const int n    = (bid - 64) & 63;
        const float* W = wsel == 0 ? Wk : (wsel == 1 ? Wq : Wv);
        WT[(size_t)(wsel * 64 + n) * 256 + tid] = (_Float16)W[tid * HH + n];
    }
}

// ---------------------------------------------------------------------------
// proj_mfma: q/k/v projections via MFMA 16x16x32_f16.
// Block = 32 rows, 4 waves N-SPLIT: wave w owns output 16-col tiles
// nt = 3w..3w+2 of 12 ([0..3]=K, [4..7]=Q, [8..11]=V) for both 16-row tiles.
// A-loads are identical across the block's waves -> L1-dedup'd; B (WT)
// traffic per wave is 4x smaller than the row-split layout.
// 2048 blocks -> 8 blocks/CU, full occupancy (latency fix for r5's 16%).
// ---------------------------------------------------------------------------
__global__ __launch_bounds__(256) void proj_mfma(
    const float* __restrict__ x, const _Float16* __restrict__ WT,
    _Float16* __restrict__ qh, _Float16* __restrict__ kh, _Float16* __restrict__ vTh)
{
    const int w    = threadIdx.x >> 6;
    const int lane = threadIdx.x & 63;
    const int quad = lane >> 4;
    const int l    = lane & 15;
    const int row0 = blockIdx.x * 32;
    const int nt0  = w * 3;

    floatx4 acc[3][2];
#pragma unroll
    for (int i = 0; i < 3; ++i)
#pragma unroll
        for (int rt = 0; rt < 2; ++rt) acc[i][rt] = (floatx4){0.f, 0.f, 0.f, 0.f};

    const float4* xg = reinterpret_cast<const float4*>(x);

#pragma unroll
    for (int kk = 0; kk < 8; ++kk) {
        const size_t base0 = (size_t)(row0 + l) * 64 + kk * 8 + quad * 2;
        const size_t base1 = base0 + 16 * 64;
        const float4 a0lo = xg[base0], a0hi = xg[base0 + 1];
        const float4 a1lo = xg[base1], a1hi = xg[base1 + 1];
        half8 af0, af1;
        af0[0] = (_Float16)a0lo.x; af0[1] = (_Float16)a0lo.y;
        af0[2] = (_Float16)a0lo.z; af0[3] = (_Float16)a0lo.w;
        af0[4] = (_Float16)a0hi.x; af0[5] = (_Float16)a0hi.y;
        af0[6] = (_Float16)a0hi.z; af0[7] = (_Float16)a0hi.w;
        af1[0] = (_Float16)a1lo.x; af1[1] = (_Float16)a1lo.y;
        af1[2] = (_Float16)a1lo.z; af1[3] = (_Float16)a1lo.w;
        af1[4] = (_Float16)a1hi.x; af1[5] = (_Float16)a1hi.y;
        af1[6] = (_Float16)a1hi.z; af1[7] = (_Float16)a1hi.w;

#pragma unroll
        for (int i = 0; i < 3; ++i) {
            const half8 bf = *(const half8*)(WT + (size_t)((nt0 + i) * 16 + l) * 256 + kk * 32 + quad * 8);
            acc[i][0] = __builtin_amdgcn_mfma_f32_16x16x32_f16(af0, bf, acc[i][0], 0, 0, 0);
            acc[i][1] = __builtin_amdgcn_mfma_f32_16x16x32_f16(af1, bf, acc[i][1], 0, 0, 0);
        }
    }

    // epilogue.  C-layout: row = quad*4 + r, col = l.
    const int bq  = row0 >> 8;
    const int trw = row0 & 255;
#pragma unroll
    for (int i = 0; i < 3; ++i) {
        const int nt = nt0 + i;
        if (nt < 8) {
            _Float16* dst = (nt < 4) ? kh : qh;
            const int col = (nt & 3) * 16 + l;
#pragma unroll
            for (int rt = 0; rt < 2; ++rt)
#pragma unroll
                for (int r = 0; r < 4; ++r) {
                    const size_t row = (size_t)row0 + rt * 16 + quad * 4 + r;
                    dst[row * HH + col] = (_Float16)acc[i][rt][r];
                }
        } else {
            const int h = (nt - 8) * 16 + l;
#pragma unroll
            for (int rt = 0; rt < 2; ++rt) {
                half4 vv;
                vv[0] = (_Float16)acc[i][rt][0];
                vv[1] = (_Float16)acc[i][rt][1];
                vv[2] = (_Float16)acc[i][rt][2];
                vv[3] = (_Float16)acc[i][rt][3];
                *(half4*)(vTh + ((size_t)bq * HH + h) * TT + trw + rt * 16 + quad * 4) = vv;
            }
        }
    }
}

// ---------------------------------------------------------------------------
// flash (pgemm fused): block = (b, 64-query tile), 4 waves x 16 rows, no
// __syncthreads (each wave owns its weih slice).
// ---------------------------------------------------------------------------
__global__ __launch_bounds__(256) void flash(
    const _Float16* __restrict__ qh, const _Float16* __restrict__ kh,
    const _Float16* __restrict__ vTh, const _Float16* __restrict__ rpeh,
    float* __restrict__ out)
{
    __shared__ _Float16 weih[4][16 * 264];   // per-wave [16 rows][256 + 8 pad]

    const int b    = blockIdx.x & 255;
    const int t0   = (blockIdx.x >> 8) * 64;
    const int w    = threadIdx.x >> 6;
    const int lane = threadIdx.x & 63;
    const int quad = lane >> 4;
    const int l    = lane & 15;
    const int tw   = t0 + 16 * w;
    const int stmax = (t0 >> 4) + w;
    const int cmax  = (tw + 15) >> 5;
    const int dtmin = 15 - (tw >> 4);

    unsigned int* wz = (unsigned int*)&weih[w][0];
#pragma unroll
    for (int i = 0; i < 33; ++i) wz[lane + 64 * i] = 0u;

    const _Float16* qp = qh + (size_t)(b * TT + tw + l) * HH + quad * 8;
    const half8 qf0 = *(const half8*)qp;
    const half8 qf1 = *(const half8*)(qp + 32);

    // P-GEMM: C-layout (row=quad*4+r, d=dt*16+l), skewed scatter into LDS
#pragma unroll
    for (int dt = 0; dt < 16; ++dt) {
        if (dt >= dtmin) {
            const _Float16* rp = rpeh + (size_t)(dt * 16 + l) * HH + quad * 8;
            const half8 bf0 = *(const half8*)rp;
            const half8 bf1 = *(const half8*)(rp + 32);
            floatx4 z = {0.f, 0.f, 0.f, 0.f};
            z = __builtin_amdgcn_mfma_f32_16x16x32_f16(qf0, bf0, z, 0, 0, 0);
            const floatx4 pacc = __builtin_amdgcn_mfma_f32_16x16x32_f16(qf1, bf1, z, 0, 0, 0);
#pragma unroll
            for (int r = 0; r < 4; ++r) {
                const int row = quad * 4 + r;
                const int s   = dt * 16 + l + (tw + row) - 255;
                if (s >= 0) weih[w][row * 264 + s] = (_Float16)pacc[r];
            }
        }
    }

    floatx4 sacc[16];
#pragma unroll
    for (int st = 0; st < 16; ++st) {
        if (st <= stmax) {
            const _Float16* kp = kh + (size_t)(b * TT + st * 16 + l) * HH + quad * 8;
            const half8 kf0 = *(const half8*)kp;
            const half8 kf1 = *(const half8*)(kp + 32);
            floatx4 z = {0.f, 0.f, 0.f, 0.f};
            z = __builtin_amdgcn_mfma_f32_16x16x32_f16(qf0, kf0, z, 0, 0, 0);
            sacc[st] = __builtin_amdgcn_mfma_f32_16x16x32_f16(qf1, kf1, z, 0, 0, 0);
        }
    }

    float inv_r[4];
#pragma unroll
    for (int r = 0; r < 4; ++r) {
        const int row = quad * 4 + r;
        const int t   = tw + row;
        float sv[16];
        float m = -INFINITY;
#pragma unroll
        for (int st = 0; st < 16; ++st) {
            if (st <= stmax) {
                const int s = l + 16 * st;
                float val = -INFINITY;
                if (s <= t) val = sacc[st][r] * 0.125f + (float)weih[w][row * 264 + s];
                sv[st] = val;
                m = fmaxf(m, val);
            }
        }
        m = fmaxf(m, __shfl_xor(m, 1));
        m = fmaxf(m, __shfl_xor(m, 2));
        m = fmaxf(m, __shfl_xor(m, 4));
        m = fmaxf(m, __shfl_xor(m, 8));
        float sum = 0.f;
#pragma unroll
        for (int st = 0; st < 16; ++st) {
            if (st <= stmax) {
                const int s = l + 16 * st;
                float e = 0.f;
                if (s <= t) e = __expf(sv[st] - m);
                sum += e;
                weih[w][row * 264 + s] = (_Float16)e;
            }
        }
        sum += __shfl_xor(sum, 1);
        sum += __shfl_xor(sum, 2);
        sum += __shfl_xor(sum, 4);
        sum += __shfl_xor(sum, 8);
        inv_r[r] = 1.0f / sum;
    }

    floatx4 oacc[4] = {{0.f,0.f,0.f,0.f},{0.f,0.f,0.f,0.f},
                       {0.f,0.f,0.f,0.f},{0.f,0.f,0.f,0.f}};
#pragma unroll
    for (int c = 0; c < 8; ++c) {
        if (c <= cmax) {
            const half8 af = *(const half8*)&weih[w][l * 264 + c * 32 + quad * 8];
#pragma unroll
            for (int ht = 0; ht < 4; ++ht) {
                const half8 vf = *(const half8*)(vTh +
                    ((size_t)b * HH + ht * 16 + l) * TT + c * 32 + quad * 8);
                oacc[ht] = __builtin_amdgcn_mfma_f32_16x16x32_f16(af, vf, oacc[ht], 0, 0, 0);
            }
        }
    }

#pragma unroll
    for (int ht = 0; ht < 4; ++ht) {
#pragma unroll
        for (int r = 0; r < 4; ++r) {
            const int t = tw + quad * 4 + r;
            out[(size_t)(b * TT + t) * HH + ht * 16 + l] = oacc[ht][r] * inv_r[r];
        }
    }
}

extern "C" void kernel_launch(void* const* d_in, const int* in_sizes, int n_in,
                              void* d_out, int out_size, void* d_ws, size_t ws_size,
                              hipStream_t stream) {
    const float* x   = (const float*)d_in[0];
    const float* Wk  = (const float*)d_in[1];
    const float* Wq  = (const float*)d_in[2];
    const float* Wv  = (const float*)d_in[3];
    const float* rpe = (const float*)d_in[4];
    float* out = (float*)d_out;

    const size_t NQ = (size_t)BB * TT * HH;
    _Float16* qh   = (_Float16*)d_ws;
    _Float16* kh   = qh + NQ;
    _Float16* vTh  = kh + NQ;
    _Float16* rpeh = vTh + NQ;
    _Float16* WT   = rpeh + 256 * HH;              // [192][256]

    prep<<<dim3(256), dim3(256), 0, stream>>>(rpe, Wk, Wq, Wv, rpeh, WT);
    proj_mfma<<<dim3(BB * TT / 32), dim3(256), 0, stream>>>(x, WT, qh, kh, vTh);
    flash<<<dim3(BB * 4), dim3(256), 0, stream>>>(qh, kh, vTh, rpeh, out);
}

// Round 7
// 177.609 us; speedup vs baseline: 1.0164x; 1.0164x over previous
//
#include <hip/hip_runtime.h>

#define BB 256
#define TT 256
#define CC 256
#define HH 64

typedef _Float16 half8 __attribute__((ext_vector_type(8)));
typedef _Float16 half4 __attribute__((ext_vector_type(4)));
typedef float floatx4 __attribute__((ext_vector_type(4)));

// ---------------------------------------------------------------------------
// prep: blocks 0..63   -> rpeh[i] = (f16) rpe[i]           (256*64 elems)
//       blocks 64..255 -> WT[(w*64+n)][k] = (f16) W_w[k][n] (transposed f16)
// ---------------------------------------------------------------------------
__global__ __launch_bounds__(256) void prep(
    const float* __restrict__ rpe,
    const float* __restrict__ Wk, const float* __restrict__ Wq, const float* __restrict__ Wv,
    _Float16* __restrict__ rpeh, _Float16* __restrict__ WT)
{
    const int bid = blockIdx.x, tid = threadIdx.x;
    if (bid < 64) {
        const int i = bid * 256 + tid;
        rpeh[i] = (_Float16)rpe[i];
    } else {
        const int wsel = (bid - 64) >> 6;          // 0=k, 1=q, 2=v
        const int n    = (bid - 64) & 63;
        const float* W = wsel == 0 ? Wk : (wsel == 1 ? Wq : Wv);
        WT[(size_t)(wsel * 64 + n) * 256 + tid] = (_Float16)W[tid * HH + n];
    }
}

// ---------------------------------------------------------------------------
// proj_mfma: q/k/v projections via MFMA 16x16x32_f16.
// Block = 64 rows, 4 waves ROW-split: wave w owns 16 rows x all 192 cols.
// (r6 post-mortem: N-split quadrupled per-MFMA A-load/cvt work; this keeps
// r5's wave-owns-all-columns efficiency and doubles wave count instead.)
// Grid 1024 -> 4 blocks/CU x 4 waves = 16 waves/CU.
// ---------------------------------------------------------------------------
__global__ __launch_bounds__(256) void proj_mfma(
    const float* __restrict__ x, const _Float16* __restrict__ WT,
    _Float16* __restrict__ qh, _Float16* __restrict__ kh, _Float16* __restrict__ vTh)
{
    const int w    = threadIdx.x >> 6;
    const int lane = threadIdx.x & 63;
    const int quad = lane >> 4;
    const int l    = lane & 15;
    const int row0 = blockIdx.x * 64 + w * 16;     // wave's 16 rows

    floatx4 acc[12];
#pragma unroll
    for (int nt = 0; nt < 12; ++nt) acc[nt] = (floatx4){0.f, 0.f, 0.f, 0.f};

    const float4* xg = reinterpret_cast<const float4*>(x);

#pragma unroll
    for (int kk = 0; kk < 8; ++kk) {
        const size_t base = (size_t)(row0 + l) * 64 + kk * 8 + quad * 2;
        const float4 alo = xg[base], ahi = xg[base + 1];
        half8 af;
        af[0] = (_Float16)alo.x; af[1] = (_Float16)alo.y;
        af[2] = (_Float16)alo.z; af[3] = (_Float16)alo.w;
        af[4] = (_Float16)ahi.x; af[5] = (_Float16)ahi.y;
        af[6] = (_Float16)ahi.z; af[7] = (_Float16)ahi.w;

#pragma unroll
        for (int nt = 0; nt < 12; ++nt) {
            const half8 bf = *(const half8*)(WT + (size_t)(nt * 16 + l) * 256 + kk * 32 + quad * 8);
            acc[nt] = __builtin_amdgcn_mfma_f32_16x16x32_f16(af, bf, acc[nt], 0, 0, 0);
        }
    }

    // epilogue.  C-layout: row = quad*4 + r, col = l.
    const int bq  = row0 >> 8;
    const int trw = row0 & 255;
#pragma unroll
    for (int nt = 0; nt < 4; ++nt) {
#pragma unroll
        for (int r = 0; r < 4; ++r) {
            const size_t row = (size_t)row0 + quad * 4 + r;
            kh[row * HH + nt * 16 + l] = (_Float16)acc[nt][r];
            qh[row * HH + nt * 16 + l] = (_Float16)acc[nt + 4][r];
        }
        half4 vv;
        vv[0] = (_Float16)acc[nt + 8][0];
        vv[1] = (_Float16)acc[nt + 8][1];
        vv[2] = (_Float16)acc[nt + 8][2];
        vv[3] = (_Float16)acc[nt + 8][3];
        *(half4*)(vTh + ((size_t)bq * HH + nt * 16 + l) * TT + trw + quad * 4) = vv;
    }
}

// ---------------------------------------------------------------------------
// flash (pgemm fused): block = (b, 64-query tile), 4 waves x 16 rows, no
// __syncthreads (each wave owns its weih slice).
// ---------------------------------------------------------------------------
__global__ __launch_bounds__(256) void flash(
    const _Float16* __restrict__ qh, const _Float16* __restrict__ kh,
    const _Float16* __restrict__ vTh, const _Float16* __restrict__ rpeh,
    float* __restrict__ out)
{
    __shared__ _Float16 weih[4][16 * 264];   // per-wave [16 rows][256 + 8 pad]

    const int b    = blockIdx.x & 255;
    const int t0   = (blockIdx.x >> 8) * 64;
    const int w    = threadIdx.x >> 6;
    const int lane = threadIdx.x & 63;
    const int quad = lane >> 4;
    const int l    = lane & 15;
    const int tw   = t0 + 16 * w;
    const int stmax = (t0 >> 4) + w;
    const int cmax  = (tw + 15) >> 5;
    const int dtmin = 15 - (tw >> 4);

    unsigned int* wz = (unsigned int*)&weih[w][0];
#pragma unroll
    for (int i = 0; i < 33; ++i) wz[lane + 64 * i] = 0u;

    const _Float16* qp = qh + (size_t)(b * TT + tw + l) * HH + quad * 8;
    const half8 qf0 = *(const half8*)qp;
    const half8 qf1 = *(const half8*)(qp + 32);

    // P-GEMM: C-layout (row=quad*4+r, d=dt*16+l), skewed scatter into LDS
#pragma unroll
    for (int dt = 0; dt < 16; ++dt) {
        if (dt >= dtmin) {
            const _Float16* rp = rpeh + (size_t)(dt * 16 + l) * HH + quad * 8;
            const half8 bf0 = *(const half8*)rp;
            const half8 bf1 = *(const half8*)(rp + 32);
            floatx4 z = {0.f, 0.f, 0.f, 0.f};
            z = __builtin_amdgcn_mfma_f32_16x16x32_f16(qf0, bf0, z, 0, 0, 0);
            const floatx4 pacc = __builtin_amdgcn_mfma_f32_16x16x32_f16(qf1, bf1, z, 0, 0, 0);
#pragma unroll
            for (int r = 0; r < 4; ++r) {
                const int row = quad * 4 + r;
                const int s   = dt * 16 + l + (tw + row) - 255;
                if (s >= 0) weih[w][row * 264 + s] = (_Float16)pacc[r];
            }
        }
    }

    floatx4 sacc[16];
#pragma unroll
    for (int st = 0; st < 16; ++st) {
        if (st <= stmax) {
            const _Float16* kp = kh + (size_t)(b * TT + st * 16 + l) * HH + quad * 8;
            const half8 kf0 = *(const half8*)kp;
            const half8 kf1 = *(const half8*)(kp + 32);
            floatx4 z = {0.f, 0.f, 0.f, 0.f};
            z = __builtin_amdgcn_mfma_f32_16x16x32_f16(qf0, kf0, z, 0, 0, 0);
            sacc[st] = __builtin_amdgcn_mfma_f32_16x16x32_f16(qf1, kf1, z, 0, 0, 0);
        }
    }

    float inv_r[4];
#pragma unroll
    for (int r = 0; r < 4; ++r) {
        const int row = quad * 4 + r;
        const int t   = tw + row;
        float sv[16];
        float m = -INFINITY;
#pragma unroll
        for (int st = 0; st < 16; ++st) {
            if (st <= stmax) {
                const int s = l + 16 * st;
                float val = -INFINITY;
                if (s <= t) val = sacc[st][r] * 0.125f + (float)weih[w][row * 264 + s];
                sv[st] = val;
                m = fmaxf(m, val);
            }
        }
        m = fmaxf(m, __shfl_xor(m, 1));
        m = fmaxf(m, __shfl_xor(m, 2));
        m = fmaxf(m, __shfl_xor(m, 4));
        m = fmaxf(m, __shfl_xor(m, 8));
        float sum = 0.f;
#pragma unroll
        for (int st = 0; st < 16; ++st) {
            if (st <= stmax) {
                const int s = l + 16 * st;
                float e = 0.f;
                if (s <= t) e = __expf(sv[st] - m);
                sum += e;
                weih[w][row * 264 + s] = (_Float16)e;
            }
        }
        sum += __shfl_xor(sum, 1);
        sum += __shfl_xor(sum, 2);
        sum += __shfl_xor(sum, 4);
        sum += __shfl_xor(sum, 8);
        inv_r[r] = 1.0f / sum;
    }

    floatx4 oacc[4] = {{0.f,0.f,0.f,0.f},{0.f,0.f,0.f,0.f},
                       {0.f,0.f,0.f,0.f},{0.f,0.f,0.f,0.f}};
#pragma unroll
    for (int c = 0; c < 8; ++c) {
        if (c <= cmax) {
            const half8 af = *(const half8*)&weih[w][l * 264 + c * 32 + quad * 8];
#pragma unroll
            for (int ht = 0; ht < 4; ++ht) {
                const half8 vf = *(const half8*)(vTh +
                    ((size_t)b * HH + ht * 16 + l) * TT + c * 32 + quad * 8);
                oacc[ht] = __builtin_amdgcn_mfma_f32_16x16x32_f16(af, vf, oacc[ht], 0, 0, 0);
            }
        }
    }

#pragma unroll
    for (int ht = 0; ht < 4; ++ht) {
#pragma unroll
        for (int r = 0; r < 4; ++r) {
            const int t = tw + quad * 4 + r;
            out[(size_t)(b * TT + t) * HH + ht * 16 + l] = oacc[ht][r] * inv_r[r];
        }
    }
}

extern "C" void kernel_launch(void* const* d_in, const int* in_sizes, int n_in,
                              void* d_out, int out_size, void* d_ws, size_t ws_size,
                              hipStream_t stream) {
    const float* x   = (const float*)d_in[0];
    const float* Wk  = (const float*)d_in[1];
    const float* Wq  = (const float*)d_in[2];
    const float* Wv  = (const float*)d_in[3];
    const float* rpe = (const float*)d_in[4];
    float* out = (float*)d_out;

    const size_t NQ = (size_t)BB * TT * HH;
    _Float16* qh   = (_Float16*)d_ws;
    _Float16* kh   = qh + NQ;
    _Float16* vTh  = kh + NQ;
    _Float16* rpeh = vTh + NQ;
    _Float16* WT   = rpeh + 256 * HH;              // [192][256]

    prep<<<dim3(256), dim3(256), 0, stream>>>(rpe, Wk, Wq, Wv, rpeh, WT);
    proj_mfma<<<dim3(BB * TT / 64), dim3(256), 0, stream>>>(x, WT, qh, kh, vTh);
    flash<<<dim3(BB * 4), dim3(256), 0, stream>>>(qh, kh, vTh, rpeh, out);
}

// Round 8
// 152.650 us; speedup vs baseline: 1.1826x; 1.1635x over previous
//
#include <hip/hip_runtime.h>

#define BB 256
#define TT 256
#define CC 256
#define HH 64

typedef _Float16 half8 __attribute__((ext_vector_type(8)));
typedef _Float16 half4 __attribute__((ext_vector_type(4)));
typedef float floatx4 __attribute__((ext_vector_type(4)));

// ---------------------------------------------------------------------------
// prep: blocks 0..63   -> rpeh[i] = (f16) rpe[i]           (256*64 elems)
//       blocks 64..255 -> WT[(w*64+n)][k] = (f16) W_w[k][n] (transposed f16)
// ---------------------------------------------------------------------------
__global__ __launch_bounds__(256) void prep(
    const float* __restrict__ rpe,
    const float* __restrict__ Wk, const float* __restrict__ Wq, const float* __restrict__ Wv,
    _Float16* __restrict__ rpeh, _Float16* __restrict__ WT)
{
    const int bid = blockIdx.x, tid = threadIdx.x;
    if (bid < 64) {
        const int i = bid * 256 + tid;
        rpeh[i] = (_Float16)rpe[i];
    } else {
        const int wsel = (bid - 64) >> 6;          // 0=k, 1=q, 2=v
        const int n    = (bid - 64) & 63;
        const float* W = wsel == 0 ? Wk : (wsel == 1 ? Wq : Wv);
        WT[(size_t)(wsel * 64 + n) * 256 + tid] = (_Float16)W[tid * HH + n];
    }
}

// ---------------------------------------------------------------------------
// proj_mfma: q/k/v projections via MFMA 16x16x32_f16, WT staged in LDS.
// r7 post-mortem: runtime tracked global-VMEM instruction count (B reloads
// from L2), not occupancy.  Fix: block = 512 threads (8 waves x 32 rows =
// 256 rows = one batch), WT (192x256 f16) staged ONCE per block into LDS
// (stride 264 halves: row stride = 4 words mod 32 -> 2-way = free; 16B
// aligned).  Per kk: 4 global A-loads + 12 ds_read_b128 + 24 MFMA.
// Grid 256 = 1 block/CU; global VMEM instrs drop 4x vs r5.
// ---------------------------------------------------------------------------
__global__ __launch_bounds__(512) void proj_mfma(
    const float* __restrict__ x, const _Float16* __restrict__ WT,
    _Float16* __restrict__ qh, _Float16* __restrict__ kh, _Float16* __restrict__ vTh)
{
    __shared__ _Float16 ws[192 * 264];
    const int tid = threadIdx.x;

    // stage WT -> LDS (12 half8 vectors per thread)
#pragma unroll
    for (int i = tid; i < 192 * 32; i += 512) {
        const int row = i >> 5;
        const int c8  = (i & 31) << 3;
        *(half8*)&ws[row * 264 + c8] = *(const half8*)(WT + (size_t)row * 256 + c8);
    }
    __syncthreads();

    const int w    = tid >> 6;
    const int lane = tid & 63;
    const int quad = lane >> 4;
    const int l    = lane & 15;
    const int row0 = blockIdx.x * 256 + w * 32;    // wave's 32 rows (one b per block)

    floatx4 acc[12][2];
#pragma unroll
    for (int nt = 0; nt < 12; ++nt)
#pragma unroll
        for (int rt = 0; rt < 2; ++rt) acc[nt][rt] = (floatx4){0.f, 0.f, 0.f, 0.f};

    const float4* xg = reinterpret_cast<const float4*>(x);

#pragma unroll
    for (int kk = 0; kk < 8; ++kk) {
        const size_t base0 = (size_t)(row0 + l) * 64 + kk * 8 + quad * 2;
        const size_t base1 = base0 + 16 * 64;
        const float4 a0lo = xg[base0], a0hi = xg[base0 + 1];
        const float4 a1lo = xg[base1], a1hi = xg[base1 + 1];
        half8 af0, af1;
        af0[0] = (_Float16)a0lo.x; af0[1] = (_Float16)a0lo.y;
        af0[2] = (_Float16)a0lo.z; af0[3] = (_Float16)a0lo.w;
        af0[4] = (_Float16)a0hi.x; af0[5] = (_Float16)a0hi.y;
        af0[6] = (_Float16)a0hi.z; af0[7] = (_Float16)a0hi.w;
        af1[0] = (_Float16)a1lo.x; af1[1] = (_Float16)a1lo.y;
        af1[2] = (_Float16)a1lo.z; af1[3] = (_Float16)a1lo.w;
        af1[4] = (_Float16)a1hi.x; af1[5] = (_Float16)a1hi.y;
        af1[6] = (_Float16)a1hi.z; af1[7] = (_Float16)a1hi.w;

#pragma unroll
        for (int nt = 0; nt < 12; ++nt) {
            const half8 bf = *(const half8*)&ws[(nt * 16 + l) * 264 + kk * 32 + quad * 8];
            acc[nt][0] = __builtin_amdgcn_mfma_f32_16x16x32_f16(af0, bf, acc[nt][0], 0, 0, 0);
            acc[nt][1] = __builtin_amdgcn_mfma_f32_16x16x32_f16(af1, bf, acc[nt][1], 0, 0, 0);
        }
    }

    // epilogue.  C-layout: row = quad*4 + r, col = l.
    const int bq  = blockIdx.x;            // block = exactly one batch
    const int trw = w * 32;
#pragma unroll
    for (int nt = 0; nt < 4; ++nt) {
#pragma unroll
        for (int rt = 0; rt < 2; ++rt) {
#pragma unroll
            for (int r = 0; r < 4; ++r) {
                const size_t row = (size_t)row0 + rt * 16 + quad * 4 + r;
                kh[row * HH + nt * 16 + l] = (_Float16)acc[nt][rt][r];
                qh[row * HH + nt * 16 + l] = (_Float16)acc[nt + 4][rt][r];
            }
            half4 vv;
            vv[0] = (_Float16)acc[nt + 8][rt][0];
            vv[1] = (_Float16)acc[nt + 8][rt][1];
            vv[2] = (_Float16)acc[nt + 8][rt][2];
            vv[3] = (_Float16)acc[nt + 8][rt][3];
            *(half4*)(vTh + ((size_t)bq * HH + nt * 16 + l) * TT + trw + rt * 16 + quad * 4) = vv;
        }
    }
}

// ---------------------------------------------------------------------------
// flash (pgemm fused): block = (b, 64-query tile), 4 waves x 16 rows, no
// __syncthreads (each wave owns its weih slice).
// ---------------------------------------------------------------------------
__global__ __launch_bounds__(256) void flash(
    const _Float16* __restrict__ qh, const _Float16* __restrict__ kh,
    const _Float16* __restrict__ vTh, const _Float16* __restrict__ rpeh,
    float* __restrict__ out)
{
    __shared__ _Float16 weih[4][16 * 264];   // per-wave [16 rows][256 + 8 pad]

    const int b    = blockIdx.x & 255;
    const int t0   = (blockIdx.x >> 8) * 64;
    const int w    = threadIdx.x >> 6;
    const int lane = threadIdx.x & 63;
    const int quad = lane >> 4;
    const int l    = lane & 15;
    const int tw   = t0 + 16 * w;
    const int stmax = (t0 >> 4) + w;
    const int cmax  = (tw + 15) >> 5;
    const int dtmin = 15 - (tw >> 4);

    unsigned int* wz = (unsigned int*)&weih[w][0];
#pragma unroll
    for (int i = 0; i < 33; ++i) wz[lane + 64 * i] = 0u;

    const _Float16* qp = qh + (size_t)(b * TT + tw + l) * HH + quad * 8;
    const half8 qf0 = *(const half8*)qp;
    const half8 qf1 = *(const half8*)(qp + 32);

    // P-GEMM: C-layout (row=quad*4+r, d=dt*16+l), skewed scatter into LDS
#pragma unroll
    for (int dt = 0; dt < 16; ++dt) {
        if (dt >= dtmin) {
            const _Float16* rp = rpeh + (size_t)(dt * 16 + l) * HH + quad * 8;
            const half8 bf0 = *(const half8*)rp;
            const half8 bf1 = *(const half8*)(rp + 32);
            floatx4 z = {0.f, 0.f, 0.f, 0.f};
            z = __builtin_amdgcn_mfma_f32_16x16x32_f16(qf0, bf0, z, 0, 0, 0);
            const floatx4 pacc = __builtin_amdgcn_mfma_f32_16x16x32_f16(qf1, bf1, z, 0, 0, 0);
#pragma unroll
            for (int r = 0; r < 4; ++r) {
                const int row = quad * 4 + r;
                const int s   = dt * 16 + l + (tw + row) - 255;
                if (s >= 0) weih[w][row * 264 + s] = (_Float16)pacc[r];
            }
        }
    }

    floatx4 sacc[16];
#pragma unroll
    for (int st = 0; st < 16; ++st) {
        if (st <= stmax) {
            const _Float16* kp = kh + (size_t)(b * TT + st * 16 + l) * HH + quad * 8;
            const half8 kf0 = *(const half8*)kp;
            const half8 kf1 = *(const half8*)(kp + 32);
            floatx4 z = {0.f, 0.f, 0.f, 0.f};
            z = __builtin_amdgcn_mfma_f32_16x16x32_f16(qf0, kf0, z, 0, 0, 0);
            sacc[st] = __builtin_amdgcn_mfma_f32_16x16x32_f16(qf1, kf1, z, 0, 0, 0);
        }
    }

    float inv_r[4];
#pragma unroll
    for (int r = 0; r < 4; ++r) {
        const int row = quad * 4 + r;
        const int t   = tw + row;
        float sv[16];
        float m = -INFINITY;
#pragma unroll
        for (int st = 0; st < 16; ++st) {
            if (st <= stmax) {
                const int s = l + 16 * st;
                float val = -INFINITY;
                if (s <= t) val = sacc[st][r] * 0.125f + (float)weih[w][row * 264 + s];
                sv[st] = val;
                m = fmaxf(m, val);
            }
        }
        m = fmaxf(m, __shfl_xor(m, 1));
        m = fmaxf(m, __shfl_xor(m, 2));
        m = fmaxf(m, __shfl_xor(m, 4));
        m = fmaxf(m, __shfl_xor(m, 8));
        float sum = 0.f;
#pragma unroll
        for (int st = 0; st < 16; ++st) {
            if (st <= stmax) {
                const int s = l + 16 * st;
                float e = 0.f;
                if (s <= t) e = __expf(sv[st] - m);
                sum += e;
                weih[w][row * 264 + s] = (_Float16)e;
            }
        }
        sum += __shfl_xor(sum, 1);
        sum += __shfl_xor(sum, 2);
        sum += __shfl_xor(sum, 4);
        sum += __shfl_xor(sum, 8);
        inv_r[r] = 1.0f / sum;
    }

    floatx4 oacc[4] = {{0.f,0.f,0.f,0.f},{0.f,0.f,0.f,0.f},
                       {0.f,0.f,0.f,0.f},{0.f,0.f,0.f,0.f}};
#pragma unroll
    for (int c = 0; c < 8; ++c) {
        if (c <= cmax) {
            const half8 af = *(const half8*)&weih[w][l * 264 + c * 32 + quad * 8];
#pragma unroll
            for (int ht = 0; ht < 4; ++ht) {
                const half8 vf = *(const half8*)(vTh +
                    ((size_t)b * HH + ht * 16 + l) * TT + c * 32 + quad * 8);
                oacc[ht] = __builtin_amdgcn_mfma_f32_16x16x32_f16(af, vf, oacc[ht], 0, 0, 0);
            }
        }
    }

#pragma unroll
    for (int ht = 0; ht < 4; ++ht) {
#pragma unroll
        for (int r = 0; r < 4; ++r) {
            const int t = tw + quad * 4 + r;
            out[(size_t)(b * TT + t) * HH + ht * 16 + l] = oacc[ht][r] * inv_r[r];
        }
    }
}

extern "C" void kernel_launch(void* const* d_in, const int* in_sizes, int n_in,
                              void* d_out, int out_size, void* d_ws, size_t ws_size,
                              hipStream_t stream) {
    const float* x   = (const float*)d_in[0];
    const float* Wk  = (const float*)d_in[1];
    const float* Wq  = (const float*)d_in[2];
    const float* Wv  = (const float*)d_in[3];
    const float* rpe = (const float*)d_in[4];
    float* out = (float*)d_out;

    const size_t NQ = (size_t)BB * TT * HH;
    _Float16* qh   = (_Float16*)d_ws;
    _Float16* kh   = qh + NQ;
    _Float16* vTh  = kh + NQ;
    _Float16* rpeh = vTh + NQ;
    _Float16* WT   = rpeh + 256 * HH;              // [192][256]

    prep<<<dim3(256), dim3(256), 0, stream>>>(rpe, Wk, Wq, Wv, rpeh, WT);
    proj_mfma<<<dim3(BB), dim3(512), 0, stream>>>(x, WT, qh, kh, vTh);
    flash<<<dim3(BB * 4), dim3(256), 0, stream>>>(qh, kh, vTh, rpeh, out);
}